// Round 5
// baseline (218.625 us; speedup 1.0000x reference)
//
#include <hip/hip_runtime.h>
#include <hip/hip_bf16.h>

// Element-wise threshold-round with reversed output order.
// y[i] = (x[i]-trunc(x[i]) > thr) ? rint(x[i]) : floor(x[i]);  out = y[::-1]
//
// Memory-bound: 128 MiB in + 128 MiB out. Both the 16B load AND the 16B
// store are lane-ascending contiguous: the output reversal is done by
// (a) swapping components within the vec4 and (b) a cross-lane shuffle
// lane l <-> lane 63-l, so each wave stores one ascending 1 KiB segment.
// Nontemporal hints: pure streaming, zero reuse. Native clang vector type
// (ext_vector_type) because __builtin_nontemporal_* rejects HIP_vector_type.
//
// NOTE (R4 post-mortem): the 2-groups-per-thread variant failed the
// harness's post-timing revalidation (d_out left as poison on replays)
// with no identifiable deterministic bug, and gained nothing — the kernel
// dispatch is <80us inside a ~160us harness-fill-dominated scored window.
// This single-stream version is the known-good roofline kernel.

typedef float vfloat4 __attribute__((ext_vector_type(4)));

__global__ __launch_bounds__(256) void threshold_rev_kernel(
    const vfloat4* __restrict__ x4,
    const float* __restrict__ threshold,
    vfloat4* __restrict__ out4,
    int n4 /* number of float4 groups = N/4 */) {
    const float thr = threshold[0];
    const int t = blockIdx.x * blockDim.x + threadIdx.x;
    if (t >= n4) return;                 // n4 is a multiple of 64; wave-uniform
    const int lane = threadIdx.x & 63;
    const int wave_base = t - lane;      // first group handled by this wave

    vfloat4 v = __builtin_nontemporal_load(&x4[t]);

    // op per element, components reversed: r = {op(v3), op(v2), op(v1), op(v0)}
    vfloat4 r;
    {
        float f = v.w - truncf(v.w);
        r.x = (f > thr) ? rintf(v.w) : floorf(v.w);
    }
    {
        float f = v.z - truncf(v.z);
        r.y = (f > thr) ? rintf(v.z) : floorf(v.z);
    }
    {
        float f = v.y - truncf(v.y);
        r.z = (f > thr) ? rintf(v.y) : floorf(v.y);
    }
    {
        float f = v.x - truncf(v.x);
        r.w = (f > thr) ? rintf(v.x) : floorf(v.x);
    }

    // lane l takes the result computed by lane 63-l, so stores ascend with lane.
    const int src = 63 - lane;
    vfloat4 s;
    s.x = __shfl(r.x, src);
    s.y = __shfl(r.y, src);
    s.z = __shfl(r.z, src);
    s.w = __shfl(r.w, src);

    // input group of lane (63-l) is wave_base + 63 - l; its output group is
    // n4-1-(wave_base+63-l) = (n4-64-wave_base) + l  -> ascending in lane.
    const int og = (n4 - 64 - wave_base) + lane;
    __builtin_nontemporal_store(s, &out4[og]);
}

extern "C" void kernel_launch(void* const* d_in, const int* in_sizes, int n_in,
                              void* d_out, int out_size, void* d_ws, size_t ws_size,
                              hipStream_t stream) {
    const vfloat4* x4 = (const vfloat4*)d_in[0];
    const float* thr = (const float*)d_in[1];
    vfloat4* out4 = (vfloat4*)d_out;
    int n = in_sizes[0];       // 33554432, divisible by 1024
    int n4 = n / 4;
    int block = 256;
    int grid = (n4 + block - 1) / block;
    threshold_rev_kernel<<<grid, block, 0, stream>>>(x4, thr, out4, n4);
}